// Round 1
// baseline (743.856 us; speedup 1.0000x reference)
//
#include <hip/hip_runtime.h>
#include <math.h>

// Problem constants
#define NN 2048      // nodes
#define NE 32768     // edges
#define INF_ 256     // input features
#define DM 128       // d_model
#define NH 16        // heads
#define CG 128       // GAT out channels per head
#define HC 2048      // NH*CG
#define DHD 8        // transformer head dim

// ---------------------------------------------------------------------------
// Generic tiled fp32 GEMM: C = act(A[M,K] @ B[K,N] + bias[N])
// ACT: 0 = none, 1 = relu, 2 = sigmoid(S[m,n]) * (acc + bias)
// Tiles: 64x64, BK=16, 256 threads, 4x4 per thread.
// Requires M%64==0, N%64==0, K%16==0 (true for all calls here).
// ---------------------------------------------------------------------------
template<int ACT>
__global__ __launch_bounds__(256)
void gemm_k(const float* __restrict__ A, const float* __restrict__ B,
            const float* __restrict__ bias, const float* __restrict__ S,
            float* __restrict__ Cm, int M, int N, int K) {
  __shared__ float As[16][64];
  __shared__ float Bs[16][64];
  const int tid = threadIdx.x;
  const int tx = tid & 15, ty = tid >> 4;
  const int m0 = blockIdx.y << 6, n0 = blockIdx.x << 6;
  const int arow = tid >> 2, akq = (tid & 3) << 2;   // A-tile loader coords
  const int brow = tid >> 4, bnq = (tid & 15) << 2;  // B-tile loader coords
  float acc[4][4] = {};
  for (int k0 = 0; k0 < K; k0 += 16) {
    float4 av = *(const float4*)(A + (size_t)(m0 + arow) * K + k0 + akq);
    float4 bv = *(const float4*)(B + (size_t)(k0 + brow) * N + n0 + bnq);
    __syncthreads();
    As[akq + 0][arow] = av.x;
    As[akq + 1][arow] = av.y;
    As[akq + 2][arow] = av.z;
    As[akq + 3][arow] = av.w;
    *(float4*)(&Bs[brow][bnq]) = bv;
    __syncthreads();
#pragma unroll
    for (int kk = 0; kk < 16; ++kk) {
      float ar[4], br[4];
#pragma unroll
      for (int i = 0; i < 4; ++i) ar[i] = As[kk][(ty << 2) + i];
#pragma unroll
      for (int j = 0; j < 4; ++j) br[j] = Bs[kk][(tx << 2) + j];
#pragma unroll
      for (int i = 0; i < 4; ++i)
#pragma unroll
        for (int j = 0; j < 4; ++j)
          acc[i][j] = fmaf(ar[i], br[j], acc[i][j]);
    }
  }
#pragma unroll
  for (int i = 0; i < 4; ++i) {
    const int row = m0 + (ty << 2) + i;
#pragma unroll
    for (int j = 0; j < 4; ++j) {
      const int col = n0 + (tx << 2) + j;
      float v = acc[i][j] + bias[col];
      if (ACT == 1) v = fmaxf(v, 0.f);
      if (ACT == 2) {
        float sg = 1.f / (1.f + __expf(-S[(size_t)row * N + col]));
        v *= sg;
      }
      Cm[(size_t)row * N + col] = v;
    }
  }
}

// ---------------------------------------------------------------------------
// CSR build: count degrees -> exclusive scan -> fill edge ids per dst node
// ---------------------------------------------------------------------------
__global__ void count_deg_k(const int* __restrict__ dst, int* __restrict__ deg) {
  int i = blockIdx.x * blockDim.x + threadIdx.x;
  if (i < NE) atomicAdd(&deg[dst[i]], 1);
}

__global__ __launch_bounds__(1024)
void scan_k(const int* __restrict__ deg, int* __restrict__ rowptr) {
  __shared__ int s[NN];
  const int t = threadIdx.x;  // 1024 threads, 2 elems each
  s[t] = deg[t];
  s[t + 1024] = deg[t + 1024];
  __syncthreads();
  for (int off = 1; off < NN; off <<= 1) {
    int v0 = (t >= off) ? s[t - off] : 0;
    int v1 = ((t + 1024) >= off) ? s[t + 1024 - off] : 0;
    __syncthreads();
    s[t] += v0;
    s[t + 1024] += v1;
    __syncthreads();
  }
  // exclusive rowptr
  if (t == 0) rowptr[0] = 0;
  rowptr[t + 1] = s[t];
  rowptr[t + 1 + 1024] = s[t + 1024];
}

__global__ void fill_csr_k(const int* __restrict__ dst, const int* __restrict__ rowptr,
                           int* __restrict__ cursor, int* __restrict__ eidx) {
  int i = blockIdx.x * blockDim.x + threadIdx.x;
  if (i < NE) {
    int d = dst[i];
    int p = atomicAdd(&cursor[d], 1);
    eidx[rowptr[d] + p] = i;
  }
}

// ---------------------------------------------------------------------------
// GAT edge logits: logits[e,h] = sum_c leaky(xl[src,h,c]+xr[dst,h,c]+ea[e]*we[h,c]) * att[h,c]
// One wave (64 lanes) per edge; each lane covers c = lane, lane+64.
// ---------------------------------------------------------------------------
__global__ __launch_bounds__(256)
void edge_logits_k(const float* __restrict__ xl, const float* __restrict__ xr,
                   const float* __restrict__ ea, const float* __restrict__ we,
                   const float* __restrict__ att, const int* __restrict__ src,
                   const int* __restrict__ dst, float* __restrict__ logits) {
  const int e = blockIdx.x * 4 + (threadIdx.x >> 6);
  const int lane = threadIdx.x & 63;
  if (e >= NE) return;
  const int s = src[e], d = dst[e];
  const float a = ea[e];
  const float* xls = xl + (size_t)s * HC;
  const float* xrd = xr + (size_t)d * HC;
#pragma unroll 4
  for (int h = 0; h < NH; ++h) {
    const int c0 = h * CG + lane;
    const int c1 = c0 + 64;
    float m0 = xls[c0] + xrd[c0] + a * we[c0];
    float m1 = xls[c1] + xrd[c1] + a * we[c1];
    m0 = m0 > 0.f ? m0 : 0.2f * m0;
    m1 = m1 > 0.f ? m1 : 0.2f * m1;
    float v = m0 * att[c0] + m1 * att[c1];
#pragma unroll
    for (int off = 32; off > 0; off >>= 1) v += __shfl_down(v, off);
    if (lane == 0) logits[(size_t)e * NH + h] = v;
  }
}

// ---------------------------------------------------------------------------
// Per-node scatter-softmax: in-place logits -> exp(logit - max); invden[n,h]=1/sum
// One wave per node; lane = h*4 + j (16 heads x 4 edge-lanes).
// ---------------------------------------------------------------------------
__global__ __launch_bounds__(64)
void node_softmax_k(float* __restrict__ logits, float* __restrict__ invden,
                    const int* __restrict__ rowptr, const int* __restrict__ eidx) {
  const int n = blockIdx.x;
  const int lane = threadIdx.x;
  const int h = lane >> 2, j = lane & 3;
  const int r0 = rowptr[n], r1 = rowptr[n + 1];
  float m = -1e30f;
  for (int i = r0 + j; i < r1; i += 4) {
    int e = eidx[i];
    m = fmaxf(m, logits[(size_t)e * NH + h]);
  }
  m = fmaxf(m, __shfl_xor(m, 1));
  m = fmaxf(m, __shfl_xor(m, 2));
  float ssum = 0.f;
  for (int i = r0 + j; i < r1; i += 4) {
    int e = eidx[i];
    float ex = __expf(logits[(size_t)e * NH + h] - m);
    logits[(size_t)e * NH + h] = ex;
    ssum += ex;
  }
  ssum += __shfl_xor(ssum, 1);
  ssum += __shfl_xor(ssum, 2);
  if (j == 0) invden[n * NH + h] = (r1 > r0) ? 1.f / ssum : 0.f;
}

// ---------------------------------------------------------------------------
// Gather-accumulate g[n,:] = invden[n,h] * sum_{e in CSR(n)} ex[e,h]*xl[src,:] + bias
// One block (256 threads) per node; thread owns 8 columns (stride 256).
// ---------------------------------------------------------------------------
__global__ __launch_bounds__(256)
void gather_g_k(const float* __restrict__ xl, const float* __restrict__ exw,
                const float* __restrict__ invden, const float* __restrict__ gat_bias,
                const int* __restrict__ rowptr, const int* __restrict__ eidx,
                const int* __restrict__ src, float* __restrict__ g) {
  const int n = blockIdx.x, t = threadIdx.x;
  const int r0 = rowptr[n], r1 = rowptr[n + 1];
  float acc[8] = {0.f, 0.f, 0.f, 0.f, 0.f, 0.f, 0.f, 0.f};
  for (int i = r0; i < r1; ++i) {
    const int e = eidx[i];
    const int s = src[e];
    const float* xs = xl + (size_t)s * HC;
    const float* exe = exw + (size_t)e * NH;
#pragma unroll
    for (int k = 0; k < 8; ++k) {
      const int col = t + (k << 8);
      acc[k] += exe[col >> 7] * xs[col];
    }
  }
#pragma unroll
  for (int k = 0; k < 8; ++k) {
    const int col = t + (k << 8);
    g[(size_t)n * HC + col] = invden[n * NH + (col >> 7)] * acc[k] + gat_bias[col];
  }
}

// ---------------------------------------------------------------------------
// Flash-style attention: H=16, DH=8, full 2048x2048 per head, online softmax.
// blockIdx.x = query tile (128 rows), blockIdx.y = head; 1 thread per query.
// Writes o'[n, h*8+d] (pre-out_proj).
// ---------------------------------------------------------------------------
__global__ __launch_bounds__(128)
void attn_k(const float* __restrict__ qkv, float* __restrict__ o) {
  const int h = blockIdx.y;
  const int q = blockIdx.x * 128 + threadIdx.x;
  __shared__ float Ks[256][8];
  __shared__ float Vs[256][8];
  const float scale = 0.35355339059327373f;  // 1/sqrt(8)
  float qv[8];
#pragma unroll
  for (int d = 0; d < 8; d += 4) {
    float4 f = *(const float4*)&qkv[(size_t)q * 384 + h * 8 + d];
    qv[d] = f.x; qv[d + 1] = f.y; qv[d + 2] = f.z; qv[d + 3] = f.w;
  }
  float m = -1e30f, l = 0.f;
  float acc[8] = {0.f, 0.f, 0.f, 0.f, 0.f, 0.f, 0.f, 0.f};
  for (int kc = 0; kc < NN; kc += 256) {
    __syncthreads();
#pragma unroll
    for (int j = 0; j < 4; ++j) {
      const int f4 = threadIdx.x + 128 * j;   // 0..511
      const int row = f4 >> 1, dc = (f4 & 1) * 4;
      *(float4*)&Ks[row][dc] =
          *(const float4*)&qkv[(size_t)(kc + row) * 384 + 128 + h * 8 + dc];
      *(float4*)&Vs[row][dc] =
          *(const float4*)&qkv[(size_t)(kc + row) * 384 + 256 + h * 8 + dc];
    }
    __syncthreads();
    for (int jj = 0; jj < 256; ++jj) {
      float4 k0 = *(float4*)&Ks[jj][0];
      float4 k1 = *(float4*)&Ks[jj][4];
      float s = qv[0] * k0.x + qv[1] * k0.y + qv[2] * k0.z + qv[3] * k0.w +
                qv[4] * k1.x + qv[5] * k1.y + qv[6] * k1.z + qv[7] * k1.w;
      s *= scale;
      if (s > m) {
        const float corr = __expf(m - s);
        l *= corr;
#pragma unroll
        for (int d = 0; d < 8; ++d) acc[d] *= corr;
        m = s;
      }
      const float w = __expf(s - m);
      l += w;
      float4 v0 = *(float4*)&Vs[jj][0];
      float4 v1 = *(float4*)&Vs[jj][4];
      acc[0] += w * v0.x; acc[1] += w * v0.y; acc[2] += w * v0.z; acc[3] += w * v0.w;
      acc[4] += w * v1.x; acc[5] += w * v1.y; acc[6] += w * v1.z; acc[7] += w * v1.w;
    }
  }
  const float rl = 1.f / l;
#pragma unroll
  for (int d = 0; d < 8; ++d) o[(size_t)q * DM + h * 8 + d] = acc[d] * rl;
}

// ---------------------------------------------------------------------------
// Residual + LayerNorm over rows of 128: out = LN(a+b)*gamma + beta
// One wave per row, 2 elems per lane.
// ---------------------------------------------------------------------------
__global__ __launch_bounds__(64)
void ln_k(const float* __restrict__ a, const float* __restrict__ b,
          const float* __restrict__ gamma, const float* __restrict__ beta,
          float* __restrict__ out) {
  const int n = blockIdx.x, lane = threadIdx.x;
  const float x0 = a[(size_t)n * DM + lane] + b[(size_t)n * DM + lane];
  const float x1 = a[(size_t)n * DM + lane + 64] + b[(size_t)n * DM + lane + 64];
  float s = x0 + x1, sq = x0 * x0 + x1 * x1;
#pragma unroll
  for (int off = 32; off > 0; off >>= 1) {
    s += __shfl_xor(s, off);
    sq += __shfl_xor(sq, off);
  }
  const float mu = s * (1.f / 128.f);
  const float var = sq * (1.f / 128.f) - mu * mu;
  const float rstd = rsqrtf(var + 1e-5f);
  out[(size_t)n * DM + lane] = (x0 - mu) * rstd * gamma[lane] + beta[lane];
  out[(size_t)n * DM + lane + 64] = (x1 - mu) * rstd * gamma[lane + 64] + beta[lane + 64];
}

// ---------------------------------------------------------------------------
// Final classifier tail: out[row, 0..1] = c1[row,:] @ w[2048,2] + b[2]
// One block (256 threads) per row.
// ---------------------------------------------------------------------------
__global__ __launch_bounds__(256)
void cls2_k(const float* __restrict__ c1, const float* __restrict__ w,
            const float* __restrict__ b, float* __restrict__ out) {
  const int row = blockIdx.x, t = threadIdx.x;
  float s0 = 0.f, s1 = 0.f;
  for (int k = t; k < HC; k += 256) {
    const float v = c1[(size_t)row * HC + k];
    s0 += v * w[k * 2];
    s1 += v * w[k * 2 + 1];
  }
#pragma unroll
  for (int off = 32; off > 0; off >>= 1) {
    s0 += __shfl_down(s0, off);
    s1 += __shfl_down(s1, off);
  }
  __shared__ float r0[4], r1[4];
  const int wv = t >> 6;
  if ((t & 63) == 0) { r0[wv] = s0; r1[wv] = s1; }
  __syncthreads();
  if (t == 0) {
    out[row * 2]     = r0[0] + r0[1] + r0[2] + r0[3] + b[0];
    out[row * 2 + 1] = r1[0] + r1[1] + r1[2] + r1[3] + b[1];
  }
}

// ---------------------------------------------------------------------------
extern "C" void kernel_launch(void* const* d_in, const int* in_sizes, int n_in,
                              void* d_out, int out_size, void* d_ws, size_t ws_size,
                              hipStream_t stream) {
  const float* x        = (const float*)d_in[0];
  const int*   eind     = (const int*)d_in[1];
  const float* ea       = (const float*)d_in[2];
  const float* enc_w1   = (const float*)d_in[3];
  const float* enc_b1   = (const float*)d_in[4];
  const float* enc_w2   = (const float*)d_in[5];
  const float* enc_b2   = (const float*)d_in[6];
  const float* gat_wl   = (const float*)d_in[7];
  const float* gat_bl   = (const float*)d_in[8];
  const float* gat_wr   = (const float*)d_in[9];
  const float* gat_br   = (const float*)d_in[10];
  const float* gat_we   = (const float*)d_in[11];
  const float* gat_att  = (const float*)d_in[12];
  const float* gat_bias = (const float*)d_in[13];
  const float* in_w     = (const float*)d_in[14];
  const float* in_b     = (const float*)d_in[15];
  const float* out_w    = (const float*)d_in[16];
  const float* out_b    = (const float*)d_in[17];
  const float* ff_w1    = (const float*)d_in[18];
  const float* ff_b1    = (const float*)d_in[19];
  const float* ff_w2    = (const float*)d_in[20];
  const float* ff_b2    = (const float*)d_in[21];
  const float* ln1_g    = (const float*)d_in[22];
  const float* ln1_b    = (const float*)d_in[23];
  const float* ln2_g    = (const float*)d_in[24];
  const float* ln2_b    = (const float*)d_in[25];
  const float* gl_w     = (const float*)d_in[26];
  const float* gl_b     = (const float*)d_in[27];
  const float* cls_w1   = (const float*)d_in[28];
  const float* cls_b1   = (const float*)d_in[29];
  const float* cls_w2   = (const float*)d_in[30];
  const float* cls_b2   = (const float*)d_in[31];

  const int* src = eind;
  const int* dst = eind + NE;

  // ---- workspace layout (floats) ----
  float* W = (float*)d_ws;
  float* enc    = W;                       // 2048*128
  float* xl     = enc    + 262144;         // 2048*2048
  float* xr     = xl     + 4194304;
  float* g      = xr     + 4194304;
  float* logits = g      + 4194304;        // 32768*16 (becomes exp() in place)
  float* invden = logits + 524288;         // 2048*16
  float* qkv    = invden + 32768;          // 2048*384
  float* attno  = qkv    + 786432;         // 2048*128
  float* obuf   = attno  + 262144;         // 2048*128  (o, later ff2)
  float* t      = obuf   + 262144;
  float* t2     = t      + 262144;
  float* ebd    = t2     + 262144;
  float* big    = ebd    + 262144;         // 2048*2048 (h1 / ff1 / c1, sequential reuse)
  int* I        = (int*)(big + 4194304);
  int* rowptr   = I;                        // NN+1
  int* deg      = I + 2052;                 // NN
  int* cursor   = I + 4100;                 // NN
  int* eidx     = I + 6148;                 // NE

  hipMemsetAsync(deg, 0, NN * sizeof(int), stream);
  hipMemsetAsync(cursor, 0, NN * sizeof(int), stream);

  dim3 b256(256);

  // ---- node encoder ----
  gemm_k<1><<<dim3(512 / 64, NN / 64), b256, 0, stream>>>(x, enc_w1, enc_b1, nullptr, big, NN, 512, INF_);
  gemm_k<0><<<dim3(DM / 64, NN / 64), b256, 0, stream>>>(big, enc_w2, enc_b2, nullptr, enc, NN, DM, 512);

  // ---- GAT projections ----
  gemm_k<0><<<dim3(HC / 64, NN / 64), b256, 0, stream>>>(enc, gat_wl, gat_bl, nullptr, xl, NN, HC, DM);
  gemm_k<0><<<dim3(HC / 64, NN / 64), b256, 0, stream>>>(enc, gat_wr, gat_br, nullptr, xr, NN, HC, DM);

  // ---- CSR build ----
  count_deg_k<<<NE / 256, b256, 0, stream>>>(dst, deg);
  scan_k<<<1, 1024, 0, stream>>>(deg, rowptr);
  fill_csr_k<<<NE / 256, b256, 0, stream>>>(dst, rowptr, cursor, eidx);

  // ---- GAT attention ----
  edge_logits_k<<<NE / 4, b256, 0, stream>>>(xl, xr, ea, gat_we, gat_att, src, dst, logits);
  node_softmax_k<<<NN, 64, 0, stream>>>(logits, invden, rowptr, eidx);
  gather_g_k<<<NN, b256, 0, stream>>>(xl, logits, invden, gat_bias, rowptr, eidx, src, g);

  // ---- transformer ----
  gemm_k<0><<<dim3(384 / 64, NN / 64), b256, 0, stream>>>(enc, in_w, in_b, nullptr, qkv, NN, 384, DM);
  attn_k<<<dim3(NN / 128, NH), 128, 0, stream>>>(qkv, attno);
  gemm_k<0><<<dim3(DM / 64, NN / 64), b256, 0, stream>>>(attno, out_w, out_b, nullptr, obuf, NN, DM, DM);
  ln_k<<<NN, 64, 0, stream>>>(enc, obuf, ln1_g, ln1_b, t);
  gemm_k<1><<<dim3(HC / 64, NN / 64), b256, 0, stream>>>(t, ff_w1, ff_b1, nullptr, big, NN, HC, DM);
  gemm_k<0><<<dim3(DM / 64, NN / 64), b256, 0, stream>>>(big, ff_w2, ff_b2, nullptr, obuf, NN, DM, HC);
  ln_k<<<NN, 64, 0, stream>>>(t, obuf, ln2_g, ln2_b, t2);

  // ---- fuse + classify ----
  gemm_k<2><<<dim3(DM / 64, NN / 64), b256, 0, stream>>>(g, gl_w, gl_b, t2, ebd, NN, DM, HC);
  gemm_k<1><<<dim3(HC / 64, NN / 64), b256, 0, stream>>>(ebd, cls_w1, cls_b1, nullptr, big, NN, HC, DM);
  cls2_k<<<NN, b256, 0, stream>>>(big, cls_w2, cls_b2, (float*)d_out);
}

// Round 2
// 566.837 us; speedup vs baseline: 1.3123x; 1.3123x over previous
//
#include <hip/hip_runtime.h>
#include <math.h>

// Problem constants
#define NN 2048      // nodes
#define NE 32768     // edges
#define INF_ 256     // input features
#define DM 128       // d_model
#define NH 16        // heads
#define CG 128       // GAT out channels per head
#define HC 2048      // NH*CG
#define DHD 8        // transformer head dim
#define NSPLIT 8     // attention key-dim splits

// ---------------------------------------------------------------------------
// Generic tiled fp32 GEMM: C = act(A[M,K] @ B[K,N] + bias[N])
// ACT: 0 = none, 1 = relu, 2 = sigmoid(S[m,n]) * (acc + bias)
// Tiles: 64x64, BK=16, 256 threads, 4x4 per thread.
// Requires M%64==0, N%64==0, K%16==0 (true for all calls here).
// ---------------------------------------------------------------------------
template<int ACT>
__global__ __launch_bounds__(256)
void gemm_k(const float* __restrict__ A, const float* __restrict__ B,
            const float* __restrict__ bias, const float* __restrict__ S,
            float* __restrict__ Cm, int M, int N, int K) {
  __shared__ float As[16][64];
  __shared__ float Bs[16][64];
  const int tid = threadIdx.x;
  const int tx = tid & 15, ty = tid >> 4;
  const int m0 = blockIdx.y << 6, n0 = blockIdx.x << 6;
  const int arow = tid >> 2, akq = (tid & 3) << 2;   // A-tile loader coords
  const int brow = tid >> 4, bnq = (tid & 15) << 2;  // B-tile loader coords
  float acc[4][4] = {};
  for (int k0 = 0; k0 < K; k0 += 16) {
    float4 av = *(const float4*)(A + (size_t)(m0 + arow) * K + k0 + akq);
    float4 bv = *(const float4*)(B + (size_t)(k0 + brow) * N + n0 + bnq);
    __syncthreads();
    As[akq + 0][arow] = av.x;
    As[akq + 1][arow] = av.y;
    As[akq + 2][arow] = av.z;
    As[akq + 3][arow] = av.w;
    *(float4*)(&Bs[brow][bnq]) = bv;
    __syncthreads();
#pragma unroll
    for (int kk = 0; kk < 16; ++kk) {
      float ar[4], br[4];
#pragma unroll
      for (int i = 0; i < 4; ++i) ar[i] = As[kk][(ty << 2) + i];
#pragma unroll
      for (int j = 0; j < 4; ++j) br[j] = Bs[kk][(tx << 2) + j];
#pragma unroll
      for (int i = 0; i < 4; ++i)
#pragma unroll
        for (int j = 0; j < 4; ++j)
          acc[i][j] = fmaf(ar[i], br[j], acc[i][j]);
    }
  }
#pragma unroll
  for (int i = 0; i < 4; ++i) {
    const int row = m0 + (ty << 2) + i;
#pragma unroll
    for (int j = 0; j < 4; ++j) {
      const int col = n0 + (tx << 2) + j;
      float v = acc[i][j] + bias[col];
      if (ACT == 1) v = fmaxf(v, 0.f);
      if (ACT == 2) {
        float sg = 1.f / (1.f + __expf(-S[(size_t)row * N + col]));
        v *= sg;
      }
      Cm[(size_t)row * N + col] = v;
    }
  }
}

// ---------------------------------------------------------------------------
// CSR build: count degrees -> exclusive scan -> fill edge ids per dst node
// ---------------------------------------------------------------------------
__global__ void count_deg_k(const int* __restrict__ dst, int* __restrict__ deg) {
  int i = blockIdx.x * blockDim.x + threadIdx.x;
  if (i < NE) atomicAdd(&deg[dst[i]], 1);
}

__global__ __launch_bounds__(1024)
void scan_k(const int* __restrict__ deg, int* __restrict__ rowptr) {
  __shared__ int s[NN];
  const int t = threadIdx.x;  // 1024 threads, 2 elems each
  s[t] = deg[t];
  s[t + 1024] = deg[t + 1024];
  __syncthreads();
  for (int off = 1; off < NN; off <<= 1) {
    int v0 = (t >= off) ? s[t - off] : 0;
    int v1 = ((t + 1024) >= off) ? s[t + 1024 - off] : 0;
    __syncthreads();
    s[t] += v0;
    s[t + 1024] += v1;
    __syncthreads();
  }
  // exclusive rowptr
  if (t == 0) rowptr[0] = 0;
  rowptr[t + 1] = s[t];
  rowptr[t + 1 + 1024] = s[t + 1024];
}

__global__ void fill_csr_k(const int* __restrict__ dst, const int* __restrict__ rowptr,
                           int* __restrict__ cursor, int* __restrict__ eidx) {
  int i = blockIdx.x * blockDim.x + threadIdx.x;
  if (i < NE) {
    int d = dst[i];
    int p = atomicAdd(&cursor[d], 1);
    eidx[rowptr[d] + p] = i;
  }
}

// ---------------------------------------------------------------------------
// GAT edge logits: logits[e,h] = sum_c leaky(xl[src,h,c]+xr[dst,h,c]+ea[e]*we[h,c]) * att[h,c]
// One wave (64 lanes) per edge; each lane covers c = lane, lane+64.
// ---------------------------------------------------------------------------
__global__ __launch_bounds__(256)
void edge_logits_k(const float* __restrict__ xl, const float* __restrict__ xr,
                   const float* __restrict__ ea, const float* __restrict__ we,
                   const float* __restrict__ att, const int* __restrict__ src,
                   const int* __restrict__ dst, float* __restrict__ logits) {
  const int e = blockIdx.x * 4 + (threadIdx.x >> 6);
  const int lane = threadIdx.x & 63;
  if (e >= NE) return;
  const int s = src[e], d = dst[e];
  const float a = ea[e];
  const float* xls = xl + (size_t)s * HC;
  const float* xrd = xr + (size_t)d * HC;
#pragma unroll 4
  for (int h = 0; h < NH; ++h) {
    const int c0 = h * CG + lane;
    const int c1 = c0 + 64;
    float m0 = xls[c0] + xrd[c0] + a * we[c0];
    float m1 = xls[c1] + xrd[c1] + a * we[c1];
    m0 = m0 > 0.f ? m0 : 0.2f * m0;
    m1 = m1 > 0.f ? m1 : 0.2f * m1;
    float v = m0 * att[c0] + m1 * att[c1];
#pragma unroll
    for (int off = 32; off > 0; off >>= 1) v += __shfl_down(v, off);
    if (lane == 0) logits[(size_t)e * NH + h] = v;
  }
}

// ---------------------------------------------------------------------------
// Per-node scatter-softmax: in-place logits -> exp(logit - max); invden[n,h]=1/sum
// One wave per node; lane = h*4 + j (16 heads x 4 edge-lanes).
// ---------------------------------------------------------------------------
__global__ __launch_bounds__(64)
void node_softmax_k(float* __restrict__ logits, float* __restrict__ invden,
                    const int* __restrict__ rowptr, const int* __restrict__ eidx) {
  const int n = blockIdx.x;
  const int lane = threadIdx.x;
  const int h = lane >> 2, j = lane & 3;
  const int r0 = rowptr[n], r1 = rowptr[n + 1];
  float m = -1e30f;
  for (int i = r0 + j; i < r1; i += 4) {
    int e = eidx[i];
    m = fmaxf(m, logits[(size_t)e * NH + h]);
  }
  m = fmaxf(m, __shfl_xor(m, 1));
  m = fmaxf(m, __shfl_xor(m, 2));
  float ssum = 0.f;
  for (int i = r0 + j; i < r1; i += 4) {
    int e = eidx[i];
    float ex = __expf(logits[(size_t)e * NH + h] - m);
    logits[(size_t)e * NH + h] = ex;
    ssum += ex;
  }
  ssum += __shfl_xor(ssum, 1);
  ssum += __shfl_xor(ssum, 2);
  if (j == 0) invden[n * NH + h] = (r1 > r0) ? 1.f / ssum : 0.f;
}

// ---------------------------------------------------------------------------
// Gather-accumulate g[n,:] = invden[n,h] * sum_{e in CSR(n)} ex[e,h]*xl[src,:] + bias
// One block (256 threads) per node; thread owns 8 columns (stride 256).
// ---------------------------------------------------------------------------
__global__ __launch_bounds__(256)
void gather_g_k(const float* __restrict__ xl, const float* __restrict__ exw,
                const float* __restrict__ invden, const float* __restrict__ gat_bias,
                const int* __restrict__ rowptr, const int* __restrict__ eidx,
                const int* __restrict__ src, float* __restrict__ g) {
  const int n = blockIdx.x, t = threadIdx.x;
  const int r0 = rowptr[n], r1 = rowptr[n + 1];
  float acc[8] = {0.f, 0.f, 0.f, 0.f, 0.f, 0.f, 0.f, 0.f};
  for (int i = r0; i < r1; ++i) {
    const int e = eidx[i];
    const int s = src[e];
    const float* xs = xl + (size_t)s * HC;
    const float* exe = exw + (size_t)e * NH;
#pragma unroll
    for (int k = 0; k < 8; ++k) {
      const int col = t + (k << 8);
      acc[k] += exe[col >> 7] * xs[col];
    }
  }
#pragma unroll
  for (int k = 0; k < 8; ++k) {
    const int col = t + (k << 8);
    g[(size_t)n * HC + col] = invden[n * NH + (col >> 7)] * acc[k] + gat_bias[col];
  }
}

// ---------------------------------------------------------------------------
// Flash-style attention, split-K over key chunks of 256.
// blockIdx.x = query tile (128 rows), blockIdx.y = head, blockIdx.z = split.
// 1 thread per query. Writes partial acc[8], m, l per (split, q, h).
// ---------------------------------------------------------------------------
__global__ __launch_bounds__(128)
void attn_split_k(const float* __restrict__ qkv, float* __restrict__ Pacc,
                  float* __restrict__ Pm, float* __restrict__ Pl) {
  const int h = blockIdx.y;
  const int q = blockIdx.x * 128 + threadIdx.x;
  const int kc = blockIdx.z * (NN / NSPLIT);  // 256-key chunk
  __shared__ float Ks[256][8];
  __shared__ float Vs[256][8];
  const float scale = 0.35355339059327373f;  // 1/sqrt(8)
  float qv[8];
#pragma unroll
  for (int d = 0; d < 8; d += 4) {
    float4 f = *(const float4*)&qkv[(size_t)q * 384 + h * 8 + d];
    qv[d] = f.x; qv[d + 1] = f.y; qv[d + 2] = f.z; qv[d + 3] = f.w;
  }
#pragma unroll
  for (int j = 0; j < 4; ++j) {
    const int f4 = threadIdx.x + 128 * j;   // 0..511
    const int row = f4 >> 1, dc = (f4 & 1) * 4;
    *(float4*)&Ks[row][dc] =
        *(const float4*)&qkv[(size_t)(kc + row) * 384 + 128 + h * 8 + dc];
    *(float4*)&Vs[row][dc] =
        *(const float4*)&qkv[(size_t)(kc + row) * 384 + 256 + h * 8 + dc];
  }
  __syncthreads();
  float m = -1e30f, l = 0.f;
  float acc[8] = {0.f, 0.f, 0.f, 0.f, 0.f, 0.f, 0.f, 0.f};
  for (int jj = 0; jj < NN / NSPLIT; ++jj) {
    float4 k0 = *(float4*)&Ks[jj][0];
    float4 k1 = *(float4*)&Ks[jj][4];
    float s = qv[0] * k0.x + qv[1] * k0.y + qv[2] * k0.z + qv[3] * k0.w +
              qv[4] * k1.x + qv[5] * k1.y + qv[6] * k1.z + qv[7] * k1.w;
    s *= scale;
    if (s > m) {
      const float corr = __expf(m - s);
      l *= corr;
#pragma unroll
      for (int d = 0; d < 8; ++d) acc[d] *= corr;
      m = s;
    }
    const float w = __expf(s - m);
    l += w;
    float4 v0 = *(float4*)&Vs[jj][0];
    float4 v1 = *(float4*)&Vs[jj][4];
    acc[0] += w * v0.x; acc[1] += w * v0.y; acc[2] += w * v0.z; acc[3] += w * v0.w;
    acc[4] += w * v1.x; acc[5] += w * v1.y; acc[6] += w * v1.z; acc[7] += w * v1.w;
  }
  const size_t i = (size_t)blockIdx.z * NN * NH + (size_t)q * NH + h;
  float* pa = Pacc + i * 8;
#pragma unroll
  for (int d = 0; d < 8; ++d) pa[d] = acc[d];
  Pm[i] = m;
  Pl[i] = l;
}

// Combine the NSPLIT partials per (q,h): one thread each.
__global__ __launch_bounds__(256)
void attn_combine_k(const float* __restrict__ Pacc, const float* __restrict__ Pm,
                    const float* __restrict__ Pl, float* __restrict__ o) {
  const int i = blockIdx.x * 256 + threadIdx.x;  // q*NH + h
  const int q = i >> 4, h = i & 15;
  float M = -1e30f;
#pragma unroll
  for (int s = 0; s < NSPLIT; ++s) M = fmaxf(M, Pm[(size_t)s * NN * NH + i]);
  float L = 0.f;
  float acc[8] = {0.f, 0.f, 0.f, 0.f, 0.f, 0.f, 0.f, 0.f};
#pragma unroll
  for (int s = 0; s < NSPLIT; ++s) {
    const float w = __expf(Pm[(size_t)s * NN * NH + i] - M);
    L += Pl[(size_t)s * NN * NH + i] * w;
    const float* pa = Pacc + ((size_t)s * NN * NH + i) * 8;
#pragma unroll
    for (int d = 0; d < 8; ++d) acc[d] += w * pa[d];
  }
  const float rl = 1.f / L;
#pragma unroll
  for (int d = 0; d < 8; ++d) o[(size_t)q * DM + h * 8 + d] = acc[d] * rl;
}

// ---------------------------------------------------------------------------
// Residual + LayerNorm over rows of 128: out = LN(a+b)*gamma + beta
// One wave per row, 2 elems per lane.
// ---------------------------------------------------------------------------
__global__ __launch_bounds__(64)
void ln_k(const float* __restrict__ a, const float* __restrict__ b,
          const float* __restrict__ gamma, const float* __restrict__ beta,
          float* __restrict__ out) {
  const int n = blockIdx.x, lane = threadIdx.x;
  const float x0 = a[(size_t)n * DM + lane] + b[(size_t)n * DM + lane];
  const float x1 = a[(size_t)n * DM + lane + 64] + b[(size_t)n * DM + lane + 64];
  float s = x0 + x1, sq = x0 * x0 + x1 * x1;
#pragma unroll
  for (int off = 32; off > 0; off >>= 1) {
    s += __shfl_xor(s, off);
    sq += __shfl_xor(sq, off);
  }
  const float mu = s * (1.f / 128.f);
  const float var = sq * (1.f / 128.f) - mu * mu;
  const float rstd = rsqrtf(var + 1e-5f);
  out[(size_t)n * DM + lane] = (x0 - mu) * rstd * gamma[lane] + beta[lane];
  out[(size_t)n * DM + lane + 64] = (x1 - mu) * rstd * gamma[lane + 64] + beta[lane + 64];
}

// ---------------------------------------------------------------------------
// Final classifier tail: out[row, 0..1] = c1[row,:] @ w[2048,2] + b[2]
// One block (256 threads) per row.
// ---------------------------------------------------------------------------
__global__ __launch_bounds__(256)
void cls2_k(const float* __restrict__ c1, const float* __restrict__ w,
            const float* __restrict__ b, float* __restrict__ out) {
  const int row = blockIdx.x, t = threadIdx.x;
  float s0 = 0.f, s1 = 0.f;
  for (int k = t; k < HC; k += 256) {
    const float v = c1[(size_t)row * HC + k];
    s0 += v * w[k * 2];
    s1 += v * w[k * 2 + 1];
  }
#pragma unroll
  for (int off = 32; off > 0; off >>= 1) {
    s0 += __shfl_down(s0, off);
    s1 += __shfl_down(s1, off);
  }
  __shared__ float r0[4], r1[4];
  const int wv = t >> 6;
  if ((t & 63) == 0) { r0[wv] = s0; r1[wv] = s1; }
  __syncthreads();
  if (t == 0) {
    out[row * 2]     = r0[0] + r0[1] + r0[2] + r0[3] + b[0];
    out[row * 2 + 1] = r1[0] + r1[1] + r1[2] + r1[3] + b[1];
  }
}

// ---------------------------------------------------------------------------
extern "C" void kernel_launch(void* const* d_in, const int* in_sizes, int n_in,
                              void* d_out, int out_size, void* d_ws, size_t ws_size,
                              hipStream_t stream) {
  const float* x        = (const float*)d_in[0];
  const int*   eind     = (const int*)d_in[1];
  const float* ea       = (const float*)d_in[2];
  const float* enc_w1   = (const float*)d_in[3];
  const float* enc_b1   = (const float*)d_in[4];
  const float* enc_w2   = (const float*)d_in[5];
  const float* enc_b2   = (const float*)d_in[6];
  const float* gat_wl   = (const float*)d_in[7];
  const float* gat_bl   = (const float*)d_in[8];
  const float* gat_wr   = (const float*)d_in[9];
  const float* gat_br   = (const float*)d_in[10];
  const float* gat_we   = (const float*)d_in[11];
  const float* gat_att  = (const float*)d_in[12];
  const float* gat_bias = (const float*)d_in[13];
  const float* in_w     = (const float*)d_in[14];
  const float* in_b     = (const float*)d_in[15];
  const float* out_w    = (const float*)d_in[16];
  const float* out_b    = (const float*)d_in[17];
  const float* ff_w1    = (const float*)d_in[18];
  const float* ff_b1    = (const float*)d_in[19];
  const float* ff_w2    = (const float*)d_in[20];
  const float* ff_b2    = (const float*)d_in[21];
  const float* ln1_g    = (const float*)d_in[22];
  const float* ln1_b    = (const float*)d_in[23];
  const float* ln2_g    = (const float*)d_in[24];
  const float* ln2_b    = (const float*)d_in[25];
  const float* gl_w     = (const float*)d_in[26];
  const float* gl_b     = (const float*)d_in[27];
  const float* cls_w1   = (const float*)d_in[28];
  const float* cls_b1   = (const float*)d_in[29];
  const float* cls_w2   = (const float*)d_in[30];
  const float* cls_b2   = (const float*)d_in[31];

  const int* src = eind;
  const int* dst = eind + NE;

  // ---- workspace layout (floats) ----
  float* W = (float*)d_ws;
  float* enc    = W;                       // 2048*128
  float* xl     = enc    + 262144;         // 2048*2048
  float* xr     = xl     + 4194304;
  float* g      = xr     + 4194304;
  float* logits = g      + 4194304;        // 32768*16 (becomes exp() in place)
  float* invden = logits + 524288;         // 2048*16
  float* qkv    = invden + 32768;          // 2048*384
  float* attno  = qkv    + 786432;         // 2048*128
  float* obuf   = attno  + 262144;         // 2048*128  (o, later ff2)
  float* t      = obuf   + 262144;
  float* t2     = t      + 262144;
  float* ebd    = t2     + 262144;
  float* big    = ebd    + 262144;         // 2048*2048 (h1 / attn partials / ff1 / c1)
  int* I        = (int*)(big + 4194304);
  int* rowptr   = I;                        // NN+1
  int* deg      = I + 2052;                 // NN
  int* cursor   = I + 4100;                 // NN
  int* eidx     = I + 6148;                 // NE

  // attention partials live in `big` (free between enc-h1 and ff1 uses)
  float* Pacc = big;                        // NSPLIT*NN*NH*8 = 2.10M floats
  float* Pm   = Pacc + NSPLIT * NN * NH * 8;  // 262144
  float* Pl   = Pm + NSPLIT * NN * NH;        // 262144  -> total 2.62M < 4.19M

  hipMemsetAsync(deg, 0, NN * sizeof(int), stream);
  hipMemsetAsync(cursor, 0, NN * sizeof(int), stream);

  dim3 b256(256);

  // ---- node encoder ----
  gemm_k<1><<<dim3(512 / 64, NN / 64), b256, 0, stream>>>(x, enc_w1, enc_b1, nullptr, big, NN, 512, INF_);
  gemm_k<0><<<dim3(DM / 64, NN / 64), b256, 0, stream>>>(big, enc_w2, enc_b2, nullptr, enc, NN, DM, 512);

  // ---- GAT projections ----
  gemm_k<0><<<dim3(HC / 64, NN / 64), b256, 0, stream>>>(enc, gat_wl, gat_bl, nullptr, xl, NN, HC, DM);
  gemm_k<0><<<dim3(HC / 64, NN / 64), b256, 0, stream>>>(enc, gat_wr, gat_br, nullptr, xr, NN, HC, DM);

  // ---- CSR build ----
  count_deg_k<<<NE / 256, b256, 0, stream>>>(dst, deg);
  scan_k<<<1, 1024, 0, stream>>>(deg, rowptr);
  fill_csr_k<<<NE / 256, b256, 0, stream>>>(dst, rowptr, cursor, eidx);

  // ---- GAT attention ----
  edge_logits_k<<<NE / 4, b256, 0, stream>>>(xl, xr, ea, gat_we, gat_att, src, dst, logits);
  node_softmax_k<<<NN, 64, 0, stream>>>(logits, invden, rowptr, eidx);
  gather_g_k<<<NN, b256, 0, stream>>>(xl, logits, invden, gat_bias, rowptr, eidx, src, g);

  // ---- transformer ----
  gemm_k<0><<<dim3(384 / 64, NN / 64), b256, 0, stream>>>(enc, in_w, in_b, nullptr, qkv, NN, 384, DM);
  attn_split_k<<<dim3(NN / 128, NH, NSPLIT), 128, 0, stream>>>(qkv, Pacc, Pm, Pl);
  attn_combine_k<<<NN * NH / 256, b256, 0, stream>>>(Pacc, Pm, Pl, attno);
  gemm_k<0><<<dim3(DM / 64, NN / 64), b256, 0, stream>>>(attno, out_w, out_b, nullptr, obuf, NN, DM, DM);
  ln_k<<<NN, 64, 0, stream>>>(enc, obuf, ln1_g, ln1_b, t);
  gemm_k<1><<<dim3(HC / 64, NN / 64), b256, 0, stream>>>(t, ff_w1, ff_b1, nullptr, big, NN, HC, DM);
  gemm_k<0><<<dim3(DM / 64, NN / 64), b256, 0, stream>>>(big, ff_w2, ff_b2, nullptr, obuf, NN, DM, HC);
  ln_k<<<NN, 64, 0, stream>>>(t, obuf, ln2_g, ln2_b, t2);

  // ---- fuse + classify ----
  gemm_k<2><<<dim3(DM / 64, NN / 64), b256, 0, stream>>>(g, gl_w, gl_b, t2, ebd, NN, DM, HC);
  gemm_k<1><<<dim3(HC / 64, NN / 64), b256, 0, stream>>>(ebd, cls_w1, cls_b1, nullptr, big, NN, HC, DM);
  cls2_k<<<NN, b256, 0, stream>>>(big, cls_w2, cls_b2, (float*)d_out);
}

// Round 3
// 381.641 us; speedup vs baseline: 1.9491x; 1.4853x over previous
//
#include <hip/hip_runtime.h>
#include <math.h>

// Problem constants
#define NN 2048      // nodes
#define NE 32768     // edges
#define INF_ 256     // input features
#define DM 128       // d_model
#define NH 16        // heads
#define CG 128       // GAT out channels per head
#define HC 2048      // NH*CG
#define DHD 8        // transformer head dim
#define NSPLIT 8     // attention key-dim splits

// ---------------------------------------------------------------------------
// Generic tiled fp32 GEMM: C = act(A[M,K] @ B[K,N] + bias[N])
// ACT: 0 = none, 1 = relu, 2 = sigmoid(S[m,n]) * (acc + bias)
// Tiles: 64x64, BK=16, 256 threads, 4x4 per thread.
// ---------------------------------------------------------------------------
template<int ACT>
__global__ __launch_bounds__(256)
void gemm_k(const float* __restrict__ A, const float* __restrict__ B,
            const float* __restrict__ bias, const float* __restrict__ S,
            float* __restrict__ Cm, int M, int N, int K) {
  __shared__ float As[16][64];
  __shared__ float Bs[16][64];
  const int tid = threadIdx.x;
  const int tx = tid & 15, ty = tid >> 4;
  const int m0 = blockIdx.y << 6, n0 = blockIdx.x << 6;
  const int arow = tid >> 2, akq = (tid & 3) << 2;   // A-tile loader coords
  const int brow = tid >> 4, bnq = (tid & 15) << 2;  // B-tile loader coords
  float acc[4][4] = {};
  for (int k0 = 0; k0 < K; k0 += 16) {
    float4 av = *(const float4*)(A + (size_t)(m0 + arow) * K + k0 + akq);
    float4 bv = *(const float4*)(B + (size_t)(k0 + brow) * N + n0 + bnq);
    __syncthreads();
    As[akq + 0][arow] = av.x;
    As[akq + 1][arow] = av.y;
    As[akq + 2][arow] = av.z;
    As[akq + 3][arow] = av.w;
    *(float4*)(&Bs[brow][bnq]) = bv;
    __syncthreads();
#pragma unroll
    for (int kk = 0; kk < 16; ++kk) {
      float ar[4], br[4];
#pragma unroll
      for (int i = 0; i < 4; ++i) ar[i] = As[kk][(ty << 2) + i];
#pragma unroll
      for (int j = 0; j < 4; ++j) br[j] = Bs[kk][(tx << 2) + j];
#pragma unroll
      for (int i = 0; i < 4; ++i)
#pragma unroll
        for (int j = 0; j < 4; ++j)
          acc[i][j] = fmaf(ar[i], br[j], acc[i][j]);
    }
  }
#pragma unroll
  for (int i = 0; i < 4; ++i) {
    const int row = m0 + (ty << 2) + i;
#pragma unroll
    for (int j = 0; j < 4; ++j) {
      const int col = n0 + (tx << 2) + j;
      float v = acc[i][j] + bias[col];
      if (ACT == 1) v = fmaxf(v, 0.f);
      if (ACT == 2) {
        float sg = 1.f / (1.f + __expf(-S[(size_t)row * N + col]));
        v *= sg;
      }
      Cm[(size_t)row * N + col] = v;
    }
  }
}

// ---------------------------------------------------------------------------
// Split-K GEMM: partial P[z][M,N] = A[M, z-chunk] @ B[z-chunk, N]
// Same tile shape as gemm_k; blockIdx.z selects the K chunk. No bias/act.
// ---------------------------------------------------------------------------
__global__ __launch_bounds__(256)
void gemm_splitk_k(const float* __restrict__ A, const float* __restrict__ B,
                   float* __restrict__ P, int M, int N, int K, int kchunk) {
  __shared__ float As[16][64];
  __shared__ float Bs[16][64];
  const int tid = threadIdx.x;
  const int tx = tid & 15, ty = tid >> 4;
  const int m0 = blockIdx.y << 6, n0 = blockIdx.x << 6;
  const int kbeg = blockIdx.z * kchunk, kend = kbeg + kchunk;
  const int arow = tid >> 2, akq = (tid & 3) << 2;
  const int brow = tid >> 4, bnq = (tid & 15) << 2;
  float acc[4][4] = {};
  for (int k0 = kbeg; k0 < kend; k0 += 16) {
    float4 av = *(const float4*)(A + (size_t)(m0 + arow) * K + k0 + akq);
    float4 bv = *(const float4*)(B + (size_t)(k0 + brow) * N + n0 + bnq);
    __syncthreads();
    As[akq + 0][arow] = av.x;
    As[akq + 1][arow] = av.y;
    As[akq + 2][arow] = av.z;
    As[akq + 3][arow] = av.w;
    *(float4*)(&Bs[brow][bnq]) = bv;
    __syncthreads();
#pragma unroll
    for (int kk = 0; kk < 16; ++kk) {
      float ar[4], br[4];
#pragma unroll
      for (int i = 0; i < 4; ++i) ar[i] = As[kk][(ty << 2) + i];
#pragma unroll
      for (int j = 0; j < 4; ++j) br[j] = Bs[kk][(tx << 2) + j];
#pragma unroll
      for (int i = 0; i < 4; ++i)
#pragma unroll
        for (int j = 0; j < 4; ++j)
          acc[i][j] = fmaf(ar[i], br[j], acc[i][j]);
    }
  }
  float* Pz = P + (size_t)blockIdx.z * M * N;
#pragma unroll
  for (int i = 0; i < 4; ++i) {
    const int row = m0 + (ty << 2) + i;
#pragma unroll
    for (int j = 0; j < 4; ++j) {
      const int col = n0 + (tx << 2) + j;
      Pz[(size_t)row * N + col] = acc[i][j];
    }
  }
}

// Reduce nsplit partials + bias + activation. ACT as in gemm_k.
template<int ACT>
__global__ __launch_bounds__(256)
void reduce_k(const float* __restrict__ P, const float* __restrict__ bias,
              const float* __restrict__ S, float* __restrict__ C,
              int MN, int N, int nsplit) {
  const int idx = blockIdx.x * 256 + threadIdx.x;
  if (idx >= MN) return;
  float v = 0.f;
  for (int s = 0; s < nsplit; ++s) v += P[(size_t)s * MN + idx];
  v += bias[idx % N];
  if (ACT == 1) v = fmaxf(v, 0.f);
  if (ACT == 2) v *= 1.f / (1.f + __expf(-S[idx]));
  C[idx] = v;
}

// ---------------------------------------------------------------------------
// CSR build: count degrees -> exclusive scan -> fill edge ids per dst node
// ---------------------------------------------------------------------------
__global__ void count_deg_k(const int* __restrict__ dst, int* __restrict__ deg) {
  int i = blockIdx.x * blockDim.x + threadIdx.x;
  if (i < NE) atomicAdd(&deg[dst[i]], 1);
}

__global__ __launch_bounds__(1024)
void scan_k(const int* __restrict__ deg, int* __restrict__ rowptr) {
  __shared__ int s[NN];
  const int t = threadIdx.x;  // 1024 threads, 2 elems each
  s[t] = deg[t];
  s[t + 1024] = deg[t + 1024];
  __syncthreads();
  for (int off = 1; off < NN; off <<= 1) {
    int v0 = (t >= off) ? s[t - off] : 0;
    int v1 = ((t + 1024) >= off) ? s[t + 1024 - off] : 0;
    __syncthreads();
    s[t] += v0;
    s[t + 1024] += v1;
    __syncthreads();
  }
  if (t == 0) rowptr[0] = 0;
  rowptr[t + 1] = s[t];
  rowptr[t + 1 + 1024] = s[t + 1024];
}

__global__ void fill_csr_k(const int* __restrict__ dst, const int* __restrict__ rowptr,
                           int* __restrict__ cursor, int* __restrict__ eidx) {
  int i = blockIdx.x * blockDim.x + threadIdx.x;
  if (i < NE) {
    int d = dst[i];
    int p = atomicAdd(&cursor[d], 1);
    eidx[rowptr[d] + p] = i;
  }
}

// ---------------------------------------------------------------------------
// GAT edge logits
// ---------------------------------------------------------------------------
__global__ __launch_bounds__(256)
void edge_logits_k(const float* __restrict__ xl, const float* __restrict__ xr,
                   const float* __restrict__ ea, const float* __restrict__ we,
                   const float* __restrict__ att, const int* __restrict__ src,
                   const int* __restrict__ dst, float* __restrict__ logits) {
  const int e = blockIdx.x * 4 + (threadIdx.x >> 6);
  const int lane = threadIdx.x & 63;
  if (e >= NE) return;
  const int s = src[e], d = dst[e];
  const float a = ea[e];
  const float* xls = xl + (size_t)s * HC;
  const float* xrd = xr + (size_t)d * HC;
#pragma unroll 4
  for (int h = 0; h < NH; ++h) {
    const int c0 = h * CG + lane;
    const int c1 = c0 + 64;
    float m0 = xls[c0] + xrd[c0] + a * we[c0];
    float m1 = xls[c1] + xrd[c1] + a * we[c1];
    m0 = m0 > 0.f ? m0 : 0.2f * m0;
    m1 = m1 > 0.f ? m1 : 0.2f * m1;
    float v = m0 * att[c0] + m1 * att[c1];
#pragma unroll
    for (int off = 32; off > 0; off >>= 1) v += __shfl_down(v, off);
    if (lane == 0) logits[(size_t)e * NH + h] = v;
  }
}

// ---------------------------------------------------------------------------
// Per-node scatter-softmax
// ---------------------------------------------------------------------------
__global__ __launch_bounds__(64)
void node_softmax_k(float* __restrict__ logits, float* __restrict__ invden,
                    const int* __restrict__ rowptr, const int* __restrict__ eidx) {
  const int n = blockIdx.x;
  const int lane = threadIdx.x;
  const int h = lane >> 2, j = lane & 3;
  const int r0 = rowptr[n], r1 = rowptr[n + 1];
  float m = -1e30f;
  for (int i = r0 + j; i < r1; i += 4) {
    int e = eidx[i];
    m = fmaxf(m, logits[(size_t)e * NH + h]);
  }
  m = fmaxf(m, __shfl_xor(m, 1));
  m = fmaxf(m, __shfl_xor(m, 2));
  float ssum = 0.f;
  for (int i = r0 + j; i < r1; i += 4) {
    int e = eidx[i];
    float ex = __expf(logits[(size_t)e * NH + h] - m);
    logits[(size_t)e * NH + h] = ex;
    ssum += ex;
  }
  ssum += __shfl_xor(ssum, 1);
  ssum += __shfl_xor(ssum, 2);
  if (j == 0) invden[n * NH + h] = (r1 > r0) ? 1.f / ssum : 0.f;
}

// ---------------------------------------------------------------------------
// Gather-accumulate g
// ---------------------------------------------------------------------------
__global__ __launch_bounds__(256)
void gather_g_k(const float* __restrict__ xl, const float* __restrict__ exw,
                const float* __restrict__ invden, const float* __restrict__ gat_bias,
                const int* __restrict__ rowptr, const int* __restrict__ eidx,
                const int* __restrict__ src, float* __restrict__ g) {
  const int n = blockIdx.x, t = threadIdx.x;
  const int r0 = rowptr[n], r1 = rowptr[n + 1];
  float acc[8] = {0.f, 0.f, 0.f, 0.f, 0.f, 0.f, 0.f, 0.f};
  for (int i = r0; i < r1; ++i) {
    const int e = eidx[i];
    const int s = src[e];
    const float* xs = xl + (size_t)s * HC;
    const float* exe = exw + (size_t)e * NH;
#pragma unroll
    for (int k = 0; k < 8; ++k) {
      const int col = t + (k << 8);
      acc[k] += exe[col >> 7] * xs[col];
    }
  }
#pragma unroll
  for (int k = 0; k < 8; ++k) {
    const int col = t + (k << 8);
    g[(size_t)n * HC + col] = invden[n * NH + (col >> 7)] * acc[k] + gat_bias[col];
  }
}

// ---------------------------------------------------------------------------
// Flash-style attention, split-K over key chunks of 256.
// ---------------------------------------------------------------------------
__global__ __launch_bounds__(128)
void attn_split_k(const float* __restrict__ qkv, float* __restrict__ Pacc,
                  float* __restrict__ Pm, float* __restrict__ Pl) {
  const int h = blockIdx.y;
  const int q = blockIdx.x * 128 + threadIdx.x;
  const int kc = blockIdx.z * (NN / NSPLIT);  // 256-key chunk
  __shared__ float Ks[256][8];
  __shared__ float Vs[256][8];
  const float scale = 0.35355339059327373f;  // 1/sqrt(8)
  float qv[8];
#pragma unroll
  for (int d = 0; d < 8; d += 4) {
    float4 f = *(const float4*)&qkv[(size_t)q * 384 + h * 8 + d];
    qv[d] = f.x; qv[d + 1] = f.y; qv[d + 2] = f.z; qv[d + 3] = f.w;
  }
#pragma unroll
  for (int j = 0; j < 4; ++j) {
    const int f4 = threadIdx.x + 128 * j;   // 0..511
    const int row = f4 >> 1, dc = (f4 & 1) * 4;
    *(float4*)&Ks[row][dc] =
        *(const float4*)&qkv[(size_t)(kc + row) * 384 + 128 + h * 8 + dc];
    *(float4*)&Vs[row][dc] =
        *(const float4*)&qkv[(size_t)(kc + row) * 384 + 256 + h * 8 + dc];
  }
  __syncthreads();
  float m = -1e30f, l = 0.f;
  float acc[8] = {0.f, 0.f, 0.f, 0.f, 0.f, 0.f, 0.f, 0.f};
  for (int jj = 0; jj < NN / NSPLIT; ++jj) {
    float4 k0 = *(float4*)&Ks[jj][0];
    float4 k1 = *(float4*)&Ks[jj][4];
    float s = qv[0] * k0.x + qv[1] * k0.y + qv[2] * k0.z + qv[3] * k0.w +
              qv[4] * k1.x + qv[5] * k1.y + qv[6] * k1.z + qv[7] * k1.w;
    s *= scale;
    if (s > m) {
      const float corr = __expf(m - s);
      l *= corr;
#pragma unroll
      for (int d = 0; d < 8; ++d) acc[d] *= corr;
      m = s;
    }
    const float w = __expf(s - m);
    l += w;
    float4 v0 = *(float4*)&Vs[jj][0];
    float4 v1 = *(float4*)&Vs[jj][4];
    acc[0] += w * v0.x; acc[1] += w * v0.y; acc[2] += w * v0.z; acc[3] += w * v0.w;
    acc[4] += w * v1.x; acc[5] += w * v1.y; acc[6] += w * v1.z; acc[7] += w * v1.w;
  }
  const size_t i = (size_t)blockIdx.z * NN * NH + (size_t)q * NH + h;
  float* pa = Pacc + i * 8;
#pragma unroll
  for (int d = 0; d < 8; ++d) pa[d] = acc[d];
  Pm[i] = m;
  Pl[i] = l;
}

// Combine the NSPLIT partials per (q,h): one thread each.
__global__ __launch_bounds__(256)
void attn_combine_k(const float* __restrict__ Pacc, const float* __restrict__ Pm,
                    const float* __restrict__ Pl, float* __restrict__ o) {
  const int i = blockIdx.x * 256 + threadIdx.x;  // q*NH + h
  const int q = i >> 4, h = i & 15;
  float M = -1e30f;
#pragma unroll
  for (int s = 0; s < NSPLIT; ++s) M = fmaxf(M, Pm[(size_t)s * NN * NH + i]);
  float L = 0.f;
  float acc[8] = {0.f, 0.f, 0.f, 0.f, 0.f, 0.f, 0.f, 0.f};
#pragma unroll
  for (int s = 0; s < NSPLIT; ++s) {
    const float w = __expf(Pm[(size_t)s * NN * NH + i] - M);
    L += Pl[(size_t)s * NN * NH + i] * w;
    const float* pa = Pacc + ((size_t)s * NN * NH + i) * 8;
#pragma unroll
    for (int d = 0; d < 8; ++d) acc[d] += w * pa[d];
  }
  const float rl = 1.f / L;
#pragma unroll
  for (int d = 0; d < 8; ++d) o[(size_t)q * DM + h * 8 + d] = acc[d] * rl;
}

// ---------------------------------------------------------------------------
// Residual + LayerNorm
// ---------------------------------------------------------------------------
__global__ __launch_bounds__(64)
void ln_k(const float* __restrict__ a, const float* __restrict__ b,
          const float* __restrict__ gamma, const float* __restrict__ beta,
          float* __restrict__ out) {
  const int n = blockIdx.x, lane = threadIdx.x;
  const float x0 = a[(size_t)n * DM + lane] + b[(size_t)n * DM + lane];
  const float x1 = a[(size_t)n * DM + lane + 64] + b[(size_t)n * DM + lane + 64];
  float s = x0 + x1, sq = x0 * x0 + x1 * x1;
#pragma unroll
  for (int off = 32; off > 0; off >>= 1) {
    s += __shfl_xor(s, off);
    sq += __shfl_xor(sq, off);
  }
  const float mu = s * (1.f / 128.f);
  const float var = sq * (1.f / 128.f) - mu * mu;
  const float rstd = rsqrtf(var + 1e-5f);
  out[(size_t)n * DM + lane] = (x0 - mu) * rstd * gamma[lane] + beta[lane];
  out[(size_t)n * DM + lane + 64] = (x1 - mu) * rstd * gamma[lane + 64] + beta[lane + 64];
}

// ---------------------------------------------------------------------------
// Final classifier tail
// ---------------------------------------------------------------------------
__global__ __launch_bounds__(256)
void cls2_k(const float* __restrict__ c1, const float* __restrict__ w,
            const float* __restrict__ b, float* __restrict__ out) {
  const int row = blockIdx.x, t = threadIdx.x;
  float s0 = 0.f, s1 = 0.f;
  for (int k = t; k < HC; k += 256) {
    const float v = c1[(size_t)row * HC + k];
    s0 += v * w[k * 2];
    s1 += v * w[k * 2 + 1];
  }
#pragma unroll
  for (int off = 32; off > 0; off >>= 1) {
    s0 += __shfl_down(s0, off);
    s1 += __shfl_down(s1, off);
  }
  __shared__ float r0[4], r1[4];
  const int wv = t >> 6;
  if ((t & 63) == 0) { r0[wv] = s0; r1[wv] = s1; }
  __syncthreads();
  if (t == 0) {
    out[row * 2]     = r0[0] + r0[1] + r0[2] + r0[3] + b[0];
    out[row * 2 + 1] = r1[0] + r1[1] + r1[2] + r1[3] + b[1];
  }
}

// ---------------------------------------------------------------------------
extern "C" void kernel_launch(void* const* d_in, const int* in_sizes, int n_in,
                              void* d_out, int out_size, void* d_ws, size_t ws_size,
                              hipStream_t stream) {
  const float* x        = (const float*)d_in[0];
  const int*   eind     = (const int*)d_in[1];
  const float* ea       = (const float*)d_in[2];
  const float* enc_w1   = (const float*)d_in[3];
  const float* enc_b1   = (const float*)d_in[4];
  const float* enc_w2   = (const float*)d_in[5];
  const float* enc_b2   = (const float*)d_in[6];
  const float* gat_wl   = (const float*)d_in[7];
  const float* gat_bl   = (const float*)d_in[8];
  const float* gat_wr   = (const float*)d_in[9];
  const float* gat_br   = (const float*)d_in[10];
  const float* gat_we   = (const float*)d_in[11];
  const float* gat_att  = (const float*)d_in[12];
  const float* gat_bias = (const float*)d_in[13];
  const float* in_w     = (const float*)d_in[14];
  const float* in_b     = (const float*)d_in[15];
  const float* out_w    = (const float*)d_in[16];
  const float* out_b    = (const float*)d_in[17];
  const float* ff_w1    = (const float*)d_in[18];
  const float* ff_b1    = (const float*)d_in[19];
  const float* ff_w2    = (const float*)d_in[20];
  const float* ff_b2    = (const float*)d_in[21];
  const float* ln1_g    = (const float*)d_in[22];
  const float* ln1_b    = (const float*)d_in[23];
  const float* ln2_g    = (const float*)d_in[24];
  const float* ln2_b    = (const float*)d_in[25];
  const float* gl_w     = (const float*)d_in[26];
  const float* gl_b     = (const float*)d_in[27];
  const float* cls_w1   = (const float*)d_in[28];
  const float* cls_b1   = (const float*)d_in[29];
  const float* cls_w2   = (const float*)d_in[30];
  const float* cls_b2   = (const float*)d_in[31];

  const int* src = eind;
  const int* dst = eind + NE;

  // ---- workspace layout (floats) ----
  float* W = (float*)d_ws;
  float* enc    = W;                       // 2048*128
  float* xl     = enc    + 262144;         // 2048*2048
  float* xr     = xl     + 4194304;        // 2048*2048; doubles as split-K scratch
  float* g      = xr     + 4194304;
  float* logits = g      + 4194304;        // 32768*16 (becomes exp() in place)
  float* invden = logits + 524288;         // 2048*16
  float* qkv    = invden + 32768;          // 2048*384
  float* attno  = qkv    + 786432;         // 2048*128
  float* obuf   = attno  + 262144;         // 2048*128  (o, later ff2)
  float* t      = obuf   + 262144;
  float* t2     = t      + 262144;
  float* ebd    = t2     + 262144;
  float* big    = ebd    + 262144;         // 2048*2048 (h1 / attn partials / ff1 / c1)
  int* I        = (int*)(big + 4194304);
  int* rowptr   = I;                        // NN+1
  int* deg      = I + 2052;                 // NN
  int* cursor   = I + 4100;                 // NN
  int* eidx     = I + 6148;                 // NE

  // attention partials live in `big` (free between enc-h1 and ff1 uses)
  float* Pacc = big;                        // NSPLIT*NN*NH*8 = 2.10M floats
  float* Pm   = Pacc + NSPLIT * NN * NH * 8;  // 262144
  float* Pl   = Pm + NSPLIT * NN * NH;        // 262144  -> total 2.62M < 4.19M

  // split-K GEMM partials live in `xr`:
  //  - enc2 (S=8, 2.1M)  : before xr written        -> safe
  //  - qkv  (S=4, 3.1M)  : after gather_g, xr dead  -> safe
  //  - out_proj/ff2/gl   : xr dead                  -> safe
  float* gemmP = xr;

  hipMemsetAsync(deg, 0, NN * sizeof(int), stream);
  hipMemsetAsync(cursor, 0, NN * sizeof(int), stream);

  dim3 b256(256);

  // ---- node encoder ----
  gemm_k<1><<<dim3(512 / 64, NN / 64), b256, 0, stream>>>(x, enc_w1, enc_b1, nullptr, big, NN, 512, INF_);
  gemm_splitk_k<<<dim3(DM / 64, NN / 64, 8), b256, 0, stream>>>(big, enc_w2, gemmP, NN, DM, 512, 64);
  reduce_k<0><<<NN * DM / 256, b256, 0, stream>>>(gemmP, enc_b2, nullptr, enc, NN * DM, DM, 8);

  // ---- GAT projections ----
  gemm_k<0><<<dim3(HC / 64, NN / 64), b256, 0, stream>>>(enc, gat_wl, gat_bl, nullptr, xl, NN, HC, DM);
  gemm_k<0><<<dim3(HC / 64, NN / 64), b256, 0, stream>>>(enc, gat_wr, gat_br, nullptr, xr, NN, HC, DM);

  // ---- CSR build ----
  count_deg_k<<<NE / 256, b256, 0, stream>>>(dst, deg);
  scan_k<<<1, 1024, 0, stream>>>(deg, rowptr);
  fill_csr_k<<<NE / 256, b256, 0, stream>>>(dst, rowptr, cursor, eidx);

  // ---- GAT attention ----
  edge_logits_k<<<NE / 4, b256, 0, stream>>>(xl, xr, ea, gat_we, gat_att, src, dst, logits);
  node_softmax_k<<<NN, 64, 0, stream>>>(logits, invden, rowptr, eidx);
  gather_g_k<<<NN, b256, 0, stream>>>(xl, logits, invden, gat_bias, rowptr, eidx, src, g);

  // ---- transformer ----
  gemm_splitk_k<<<dim3(384 / 64, NN / 64, 4), b256, 0, stream>>>(enc, in_w, gemmP, NN, 384, DM, 32);
  reduce_k<0><<<NN * 384 / 256, b256, 0, stream>>>(gemmP, in_b, nullptr, qkv, NN * 384, 384, 4);
  attn_split_k<<<dim3(NN / 128, NH, NSPLIT), 128, 0, stream>>>(qkv, Pacc, Pm, Pl);
  attn_combine_k<<<NN * NH / 256, b256, 0, stream>>>(Pacc, Pm, Pl, attno);
  gemm_splitk_k<<<dim3(DM / 64, NN / 64, 4), b256, 0, stream>>>(attno, out_w, gemmP, NN, DM, DM, 32);
  reduce_k<0><<<NN * DM / 256, b256, 0, stream>>>(gemmP, out_b, nullptr, obuf, NN * DM, DM, 4);
  ln_k<<<NN, 64, 0, stream>>>(enc, obuf, ln1_g, ln1_b, t);
  gemm_k<1><<<dim3(HC / 64, NN / 64), b256, 0, stream>>>(t, ff_w1, ff_b1, nullptr, big, NN, HC, DM);
  gemm_splitk_k<<<dim3(DM / 64, NN / 64, 16), b256, 0, stream>>>(big, ff_w2, gemmP, NN, DM, HC, 128);
  reduce_k<0><<<NN * DM / 256, b256, 0, stream>>>(gemmP, ff_b2, nullptr, obuf, NN * DM, DM, 16);
  ln_k<<<NN, 64, 0, stream>>>(t, obuf, ln2_g, ln2_b, t2);

  // ---- fuse + classify ----
  gemm_splitk_k<<<dim3(DM / 64, NN / 64, 16), b256, 0, stream>>>(g, gl_w, gemmP, NN, DM, HC, 128);
  reduce_k<2><<<NN * DM / 256, b256, 0, stream>>>(gemmP, gl_b, t2, ebd, NN * DM, DM, 16);
  gemm_k<1><<<dim3(HC / 64, NN / 64), b256, 0, stream>>>(ebd, cls_w1, cls_b1, nullptr, big, NN, HC, DM);
  cls2_k<<<NN, b256, 0, stream>>>(big, cls_w2, cls_b2, (float*)d_out);
}